// Round 13
// baseline (142.178 us; speedup 1.0000x reference)
//
#include <hip/hip_runtime.h>
#include <hip/hip_bf16.h>
#include <math.h>

#define LWAV   480000
#define XHALF  240512      // xpad length / 2
#define NBATCH 32
#define TOUT   1000
#define NMEL   64
#define PSTR   576
#define SPECW  1024

// workspace layout (bytes), 16B-aligned
#define XPE_OFF  0u           // 32*240512*2 = 15,392,768
#define XPO_OFF  15392768u    // 32*240512*2 -> 30,785,536
#define WEO_OFF  30785536u    // 1024*512*2  -> 31,834,112
#define WMT_OFF  31834112u    // 64*576*2    -> 31,907,840
#define PW_OFF   31907840u    // 32000*576*2 -> 68,771,840
#define LM_OFF   68771840u    // 32000*64*4  -> 76,963,840
#define W256_OFF 76963840u    // 1024*2      -> 76,965,888

typedef __attribute__((ext_vector_type(8))) __bf16 bf16x8;
typedef __attribute__((ext_vector_type(8))) unsigned short ushort8;
typedef __attribute__((ext_vector_type(4))) float  f32x4;

__device__ __forceinline__ void gload16(const void* g, void* l) {
  __builtin_amdgcn_global_load_lds((const __attribute__((address_space(1))) void*)g,
                                   (__attribute__((address_space(3))) void*)l, 16, 0, 0);
}
#define WAIT_VM(n)  asm volatile("s_waitcnt vmcnt(" #n ")" ::: "memory")
#define WAIT_LGKM0  asm volatile("s_waitcnt lgkmcnt(0)" ::: "memory")
#define BAR() __builtin_amdgcn_s_barrier()

__device__ __forceinline__ float bf2f(unsigned short u) {
  return __uint_as_float((unsigned)u << 16);
}

// ---------------- prepass: even/odd split + radix-2 weight tables ----------------
#define NG1 (NBATCH * (XHALF / 8))   // 962,048
#define NG2 ((1024 * 512) / 8)       // 65,536
#define NG3 ((NMEL * PSTR) / 8)      // 4,608
#define NG4 (1024 / 8)               // 128

__global__ void prep_kernel(const float* __restrict__ wav,
                            const float* __restrict__ wstft,
                            const float* __restrict__ mf,
                            unsigned char* __restrict__ ws) {
  __hip_bfloat16* xpE = (__hip_bfloat16*)(ws + XPE_OFF);
  __hip_bfloat16* xpO = (__hip_bfloat16*)(ws + XPO_OFF);
  __hip_bfloat16* weo = (__hip_bfloat16*)(ws + WEO_OFF);
  __hip_bfloat16* wmt = (__hip_bfloat16*)(ws + WMT_OFF);
  __hip_bfloat16* w256 = (__hip_bfloat16*)(ws + W256_OFF);
  int idx = blockIdx.x * blockDim.x + threadIdx.x;
  if (idx < NG1) {
    int b = idx / (XHALF / 8);
    int g = idx - b * (XHALF / 8);       // xpad positions [16g, 16g+16)
    const float* src = wav + (size_t)b * LWAV;
    __hip_bfloat16 e[8], o[8];
    if (g >= 32 && g <= 30030) {
      const float4* p = (const float4*)(src + 16 * g - 512);
#pragma unroll
      for (int u = 0; u < 4; ++u) {
        float4 v = p[u];
        e[2 * u]     = __float2bfloat16(v.x);
        o[2 * u]     = __float2bfloat16(v.y);
        e[2 * u + 1] = __float2bfloat16(v.z);
        o[2 * u + 1] = __float2bfloat16(v.w);
      }
    } else {
      for (int i = 0; i < 16; ++i) {
        int q = 16 * g + i;
        int s = q - 512;
        if (s < 0) s = -s;
        else if (s >= LWAV) s = 2 * (LWAV - 1) - s;
        __hip_bfloat16 v = __float2bfloat16(src[s]);
        if (i & 1) o[i >> 1] = v; else e[i >> 1] = v;
      }
    }
    *(uint4*)(xpE + (size_t)b * XHALF + 8 * g) = *(const uint4*)e;
    *(uint4*)(xpO + (size_t)b * XHALF + 8 * g) = *(const uint4*)o;
  } else if (idx < NG1 + NG2) {
    int v = idx - NG1;
    int row = v >> 6;                 // 0..1023 = comp*256 + j
    int mseg = (v & 63) * 8;
    int comp = row >> 8, j = row & 255;
    __hip_bfloat16 t[8];
    if (comp < 2) {
      const float4* srow = (const float4*)(wstft + (size_t)(comp == 0 ? j : 513 + j) * 1024 + 2 * mseg);
#pragma unroll
      for (int u = 0; u < 4; ++u) {
        float4 vv = srow[u];
        t[2 * u]     = __float2bfloat16(vv.x);
        t[2 * u + 1] = __float2bfloat16(vv.z);
      }
    } else {
      const float4* w0 = (const float4*)(wstft + 2 * mseg);
#pragma unroll
      for (int u = 0; u < 4; ++u) {
        float4 wwv = w0[u];
        float wo[2] = {wwv.y, wwv.w};
#pragma unroll
        for (int h = 0; h < 2; ++h) {
          int mm = mseg + 2 * u + h;
          int q = (j * mm) & 511;
          float ang = (float)q * 0.012271846f;    // 2*pi/512
          float val = (comp == 2) ? wo[h] * cosf(ang) : -wo[h] * sinf(ang);
          t[2 * u + h] = __float2bfloat16(val);
        }
      }
    }
    *(uint4*)(weo + (size_t)row * 512 + mseg) = *(const uint4*)t;
  } else if (idx < NG1 + NG2 + NG3) {
    int j = idx - NG1 - NG2;
    int n = j / (PSTR / 8);
    int k0 = (j - n * (PSTR / 8)) * 8;
    for (int k = k0; k < k0 + 8; ++k)
      wmt[n * PSTR + k] = __float2bfloat16(k < 513 ? mf[k * NMEL + n] : 0.0f);
  } else if (idx < NG1 + NG2 + NG3 + NG4) {
    int j = idx - NG1 - NG2 - NG3;
    int part = j >> 6;
    int m0 = (j & 63) * 8;
    __hip_bfloat16 t[8];
#pragma unroll
    for (int h = 0; h < 8; ++h) {
      int m = m0 + h;
      float v = part == 0 ? wstft[(size_t)256 * 1024 + 2 * m]
                          : wstft[(size_t)769 * 1024 + 2 * m + 1];
      t[h] = __float2bfloat16(v);
    }
    *(uint4*)(w256 + part * 512 + m0) = *(const uint4*)t;
  }
}

// ---------------- bin-256 kernel: writes pw[m][256] ----------------
__launch_bounds__(256, 2)
__global__ void p256_kernel(unsigned char* __restrict__ ws) {
  __hip_bfloat16* pw = (__hip_bfloat16*)(ws + PW_OFF);
  const int tid  = threadIdx.x;
  const int l16  = tid & 15;
  const int fidx = blockIdx.x * 16 + (tid >> 4);
  const int b = fidx / 1000, t = fidx - b * 1000;

  const unsigned short* xe = (const unsigned short*)(ws + XPE_OFF) +
      (size_t)b * XHALF + 240 * (size_t)t + l16 * 32;
  const unsigned short* xo = (const unsigned short*)(ws + XPO_OFF) +
      (size_t)b * XHALF + 240 * (size_t)t + l16 * 32;
  const unsigned short* we = (const unsigned short*)(ws + W256_OFF) + l16 * 32;
  const unsigned short* wo = (const unsigned short*)(ws + W256_OFF) + 512 + l16 * 32;

  ushort8 ev[4], ov[4], wev[4], wov[4];
#pragma unroll
  for (int q = 0; q < 4; ++q) {
    ev[q]  = *(const ushort8*)(xe + q * 8);
    ov[q]  = *(const ushort8*)(xo + q * 8);
    wev[q] = *(const ushort8*)(we + q * 8);
    wov[q] = *(const ushort8*)(wo + q * 8);
  }
  float dc = 0.f, ds = 0.f;
#pragma unroll
  for (int q = 0; q < 4; ++q)
#pragma unroll
    for (int u = 0; u < 8; ++u) {
      dc += bf2f(ev[q][u]) * bf2f(wev[q][u]);
      ds += bf2f(ov[q][u]) * bf2f(wov[q][u]);
    }
#pragma unroll
  for (int d = 1; d < 16; d <<= 1) {
    dc += __shfl_xor(dc, d);
    ds += __shfl_xor(ds, d);
  }
  if (l16 == 0)
    pw[((size_t)b * TOUT + t) * PSTR + 256] = __float2bfloat16(dc * dc + ds * ds);
}

// ---------------- STFT radix-2 GEMM: BM=128, 64 j x {Ec,Es,Oc,Os}, K=512, BK=32 ----
// 256 threads, 4 waves (2M x 2J). LDS holds A ONLY (dbuf 2x16KB = 32KB); B is
// loaded straight from L2 into registers with a 1-ktile prefetch (bX/bY swap)
// hidden under the MFMA phase. Halves LDS traffic (the measured R12 wall).
// vmcnt ledger (in-order retirement): steady-state retire-A-stage = vmcnt(12)
// (8 newer B loads + 4 newer A loads); tail = vmcnt(8).
#define STFT_NWG 1000
__launch_bounds__(256, 2)
__global__ void stft_kernel(unsigned char* __restrict__ ws) {
  __shared__ __align__(16) unsigned char lds[32768];  // A buf c @ c*16384
  __hip_bfloat16* pw = (__hip_bfloat16*)(ws + PW_OFF);

  const int tid  = threadIdx.x;
  const int lane = tid & 63;
  const int w    = tid >> 6;     // wave 0..3
  const int wm   = w >> 1;       // 0..1 m-half (64 frames)
  const int wn   = w & 1;        // 0..1 j-half (32 j)

  // bijective XCD-chunked swizzle (nwg=1000: q=125, r=0), j-tile fastest
  const int orig = blockIdx.x;
  const int wg = (orig & 7) * 125 + (orig >> 3);
  const int j0 = (wg & 3) * 64;
  const int m0 = (wg >> 2) * 128;

  // ---- A staging sources: 4 loads per thread per ktile (pre-swizzled) ----
  const unsigned char* gsA[4];
  {
    int sl  = tid & 7;
    int rq  = tid >> 3;            // row within 32-row group
    int slp = sl ^ (rq & 7);
#pragma unroll
    for (int i = 0; i < 4; ++i) {
      int row = i * 32 + rq;
      int m = m0 + row;
      int bb = m / 1000, tt = m - bb * 1000;
      size_t fb = ((size_t)bb * XHALF + 240 * (size_t)tt) * 2;
      gsA[i] = (slp < 4) ? (ws + XPE_OFF + fb + slp * 16)
                         : (ws + XPO_OFF + fb + (slp - 4) * 16);
    }
  }

#define STG_A(c, kt) do {                                                  \
    gload16(gsA[0] + (size_t)(kt) * 64, lds + (c) * 16384 + 0 * 4096 + w * 1024); \
    gload16(gsA[1] + (size_t)(kt) * 64, lds + (c) * 16384 + 1 * 4096 + w * 1024); \
    gload16(gsA[2] + (size_t)(kt) * 64, lds + (c) * 16384 + 2 * 4096 + w * 1024); \
    gload16(gsA[3] + (size_t)(kt) * 64, lds + (c) * 16384 + 3 * 4096 + w * 1024); \
  } while (0)

  // ---- B direct-from-global row pointers (8 per thread) ----
  const int l15 = lane & 15, lc = lane >> 4;   // lc = K chunk 0..3
  const unsigned char* gsBrow[8];
#pragma unroll
  for (int nf = 0; nf < 8; ++nf) {
    int row2 = wn * 128 + nf * 16 + l15;
    int comp = (row2 >> 4) & 3;
    int jj = j0 + (row2 >> 6) * 16 + (row2 & 15);
    gsBrow[nf] = ws + WEO_OFF + (size_t)(comp * 256 + jj) * 1024 + lc * 16;
  }
#define LOAD_B(dst, kt) do {                                               \
    _Pragma("unroll")                                                      \
    for (int nf = 0; nf < 8; ++nf)                                         \
      dst[nf] = *(const bf16x8*)(gsBrow[nf] + (size_t)(kt) * 64);          \
  } while (0)

  // A fragment read base: row = wm*64 + mf*16 + l15; E slot = lc^(l15&7); O = ^64
  const int aoffs = (wm * 64 + l15) * 128 + ((lc ^ (l15 & 7)) << 4);

  bf16x8 ae[4], ao[4], bX[8], bY[8];
  f32x4 acc[4][8];
#pragma unroll
  for (int a = 0; a < 4; ++a)
#pragma unroll
    for (int b2 = 0; b2 < 8; ++b2) acc[a][b2] = (f32x4){0.f, 0.f, 0.f, 0.f};

#define RD_A(C) do {                                                       \
    _Pragma("unroll")                                                      \
    for (int mf = 0; mf < 4; ++mf) {                                       \
      ae[mf] = *(const bf16x8*)(lds + (C) + aoffs + mf * 2048);            \
      ao[mf] = *(const bf16x8*)(lds + (C) + (aoffs ^ 64) + mf * 2048);     \
    }                                                                      \
  } while (0)

#define MFMA_ALL(B) do {                                                   \
    __builtin_amdgcn_s_setprio(1);                                         \
    _Pragma("unroll")                                                      \
    for (int mf = 0; mf < 4; ++mf)                                         \
      _Pragma("unroll")                                                    \
      for (int g = 0; g < 2; ++g) {                                        \
        acc[mf][g*4+0] = __builtin_amdgcn_mfma_f32_16x16x32_bf16(          \
            ae[mf], B[g*4+0], acc[mf][g*4+0], 0, 0, 0);                    \
        acc[mf][g*4+1] = __builtin_amdgcn_mfma_f32_16x16x32_bf16(          \
            ae[mf], B[g*4+1], acc[mf][g*4+1], 0, 0, 0);                    \
        acc[mf][g*4+2] = __builtin_amdgcn_mfma_f32_16x16x32_bf16(          \
            ao[mf], B[g*4+2], acc[mf][g*4+2], 0, 0, 0);                    \
        acc[mf][g*4+3] = __builtin_amdgcn_mfma_f32_16x16x32_bf16(          \
            ao[mf], B[g*4+3], acc[mf][g*4+3], 0, 0, 0);                    \
      }                                                                    \
    __builtin_amdgcn_s_setprio(0);                                         \
  } while (0)

  // prologue: A k0->buf0, A k1->buf1 (8 loads), B k0 -> bX (8 loads); retire A(k0)
  STG_A(0, 0);
  STG_A(1, 1);
  LOAD_B(bX, 0);
  WAIT_VM(12);
  BAR();

  for (int i = 0; i < 8; ++i) {
    const bool more = (i < 7);
    // ---- even ktile 2i (A in buf0, B in bX) ----
    RD_A(0);
    LOAD_B(bY, 2 * i + 1);
    MFMA_ALL(bX);
    WAIT_LGKM0;
    BAR();                                    // all waves done reading buf0
    if (more) {
      STG_A(0, (size_t)(2 * i + 2));          // overwrite buf0 with A(k+2)
      WAIT_VM(12);                            // retire A(2i+1)
    } else {
      WAIT_VM(8);                             // tail: retire A(15); bY(B15) newer
    }
    BAR();
    // ---- odd ktile 2i+1 (A in buf1, B in bY) ----
    RD_A(16384);
    if (more) LOAD_B(bX, 2 * i + 2);
    MFMA_ALL(bY);
    if (more) {
      WAIT_LGKM0;
      BAR();
      STG_A(1, (size_t)(2 * i + 3));
      WAIT_VM(12);                            // retire A(2i+2)
      BAR();
    }
  }

  // epilogue: twiddle-combine -> power bins j and 512-j
#pragma unroll
  for (int g = 0; g < 2; ++g) {
    int j = j0 + wn * 32 + g * 16 + l15;
    float th = (float)j * 0.0061359233f;   // pi/512
    float ct = cosf(th), st = sinf(th);
#pragma unroll
    for (int mf = 0; mf < 4; ++mf)
#pragma unroll
      for (int r = 0; r < 4; ++r) {
        int m = m0 + wm * 64 + mf * 16 + lc * 4 + r;
        float Ec = acc[mf][g*4+0][r], Es = acc[mf][g*4+1][r];
        float Oc = acc[mf][g*4+2][r], Os = acc[mf][g*4+3][r];
        float tOc = ct * Oc + st * Os;
        float tOs = ct * Os - st * Oc;
        float re1 = Ec + tOc, im1 = Es + tOs;
        float re2 = Ec - tOc, im2 = Es - tOs;
        pw[(size_t)m * PSTR + j]         = __float2bfloat16(re1 * re1 + im1 * im1);
        pw[(size_t)m * PSTR + (512 - j)] = __float2bfloat16(re2 * re2 + im2 * im2);
      }
  }
}

// ---------------- mel GEMM (K=576, BM=64) + log10 epilogue ----------------
__launch_bounds__(256, 4)
__global__ void mel_kernel(unsigned char* __restrict__ ws) {
  __shared__ __align__(16) unsigned char sA[64 * 128];
  __shared__ __align__(16) unsigned char sBt[64 * 128];
  const unsigned char* pwb  = ws + PW_OFF;
  const unsigned char* wmtb = ws + WMT_OFF;
  float* lm = (float*)(ws + LM_OFF);

  const int tid = threadIdx.x;
  const int lane = tid & 63;
  const int wid  = tid >> 6;
  const int m0 = blockIdx.x * 64;

  const int strow = tid >> 3;
  const int scol  = (tid & 7) << 4;

  const unsigned char* aptr[2];
  const unsigned char* bptr[2];
  unsigned char* aldst[2];
  unsigned char* bldst[2];
#pragma unroll
  for (int jj = 0; jj < 2; ++jj) {
    int rr = jj * 32 + strow;
    aptr[jj] = pwb + (size_t)(m0 + rr) * (PSTR * 2) + (scol ^ ((rr & 7) << 4));
    bptr[jj] = wmtb + (size_t)rr * (PSTR * 2) + (scol ^ ((rr & 7) << 4));
    aldst[jj] = &sA [jj * 4096 + wid * 1024];
    bldst[jj] = &sBt[jj * 4096 + wid * 1024];
  }

  f32x4 acc[4];
#pragma unroll
  for (int fr = 0; fr < 4; ++fr) acc[fr] = (f32x4){0.f, 0.f, 0.f, 0.f};

  for (int kk = 0; kk < PSTR; kk += 64) {
    __syncthreads();
#pragma unroll
    for (int jj = 0; jj < 2; ++jj) gload16(aptr[jj] + (size_t)kk * 2, aldst[jj]);
#pragma unroll
    for (int jj = 0; jj < 2; ++jj) gload16(bptr[jj] + (size_t)kk * 2, bldst[jj]);
    __syncthreads();
#pragma unroll
    for (int ks = 0; ks < 2; ++ks) {
      const int kby = ks * 64 + ((lane >> 4) << 4);
      bf16x8 af, bfr[4];
      {
        int rr = wid * 16 + (lane & 15);
        af = *(const bf16x8*)&sA[rr * 128 + (kby ^ ((rr & 7) << 4))];
      }
#pragma unroll
      for (int fr = 0; fr < 4; ++fr) {
        int rr = fr * 16 + (lane & 15);
        bfr[fr] = *(const bf16x8*)&sBt[rr * 128 + (kby ^ ((rr & 7) << 4))];
      }
#pragma unroll
      for (int fr = 0; fr < 4; ++fr)
        acc[fr] = __builtin_amdgcn_mfma_f32_16x16x32_bf16(af, bfr[fr], acc[fr], 0, 0, 0);
    }
  }

  const int col = lane & 15;
  const int rg  = lane >> 4;
#pragma unroll
  for (int fr = 0; fr < 4; ++fr) {
    int n = fr * 16 + col;
#pragma unroll
    for (int rr = 0; rr < 4; ++rr) {
      int mrow = wid * 16 + rg * 4 + rr;
      float v = acc[fr][rr];
      lm[(size_t)(m0 + mrow) * NMEL + n] = 10.0f * log10f(fmaxf(v, 1e-10f));
    }
  }
}

// ---------------- bilinear (time-axis only) interp ----------------
__global__ void interp_kernel(const unsigned char* __restrict__ ws, float* __restrict__ out) {
  const float* lm = (const float*)(ws + LM_OFF);
  int idx = blockIdx.x * blockDim.x + threadIdx.x;
  if (idx >= NBATCH * SPECW * 16) return;
  int m4 = idx & 15;
  int h  = (idx >> 4) & (SPECW - 1);
  int b  = idx >> 14;
  const float scale = (float)(999.0 / 1023.0);
  float pos = (float)h * scale;
  int i0 = (int)floorf(pos);
  if (i0 > TOUT - 1) i0 = TOUT - 1;
  float wgt = pos - (float)i0;
  int i1 = i0 + 1;
  if (i1 > TOUT - 1) i1 = TOUT - 1;
  const float4* r0 = (const float4*)(lm + ((size_t)b * TOUT + i0) * NMEL);
  const float4* r1 = (const float4*)(lm + ((size_t)b * TOUT + i1) * NMEL);
  float4 a = r0[m4], c = r1[m4];
  float4 o;
  o.x = a.x * (1.0f - wgt) + c.x * wgt;
  o.y = a.y * (1.0f - wgt) + c.y * wgt;
  o.z = a.z * (1.0f - wgt) + c.z * wgt;
  o.w = a.w * (1.0f - wgt) + c.w * wgt;
  ((float4*)out)[idx] = o;
}

extern "C" void kernel_launch(void* const* d_in, const int* in_sizes, int n_in,
                              void* d_out, int out_size, void* d_ws, size_t ws_size,
                              hipStream_t stream) {
  (void)in_sizes; (void)n_in; (void)out_size; (void)ws_size;
  const float* wav   = (const float*)d_in[0];
  const float* wstft = (const float*)d_in[1];
  const float* mf    = (const float*)d_in[2];
  unsigned char* ws  = (unsigned char*)d_ws;
  float* out = (float*)d_out;

  const int tot = NG1 + NG2 + NG3 + NG4;
  prep_kernel<<<(tot + 255) / 256, 256, 0, stream>>>(wav, wstft, mf, ws);
  stft_kernel<<<STFT_NWG, 256, 0, stream>>>(ws);
  p256_kernel<<<2000, 256, 0, stream>>>(ws);
  mel_kernel<<<500, 256, 0, stream>>>(ws);
  interp_kernel<<<(NBATCH * SPECW * 16) / 256, 256, 0, stream>>>(ws, out);
}

// Round 14
// 135.394 us; speedup vs baseline: 1.0501x; 1.0501x over previous
//
#include <hip/hip_runtime.h>
#include <hip/hip_bf16.h>
#include <math.h>

#define LWAV   480000
#define XHALF  240512      // xpad length / 2
#define NBATCH 32
#define TOUT   1000
#define NMEL   64
#define PSTR   576
#define SPECW  1024

// workspace layout (bytes), 16B-aligned
#define XPE_OFF  0u           // 32*240512*2 = 15,392,768
#define XPO_OFF  15392768u    // 32*240512*2 -> 30,785,536
#define WEO_OFF  30785536u    // 1024*512*2  -> 31,834,112
#define WMT_OFF  31834112u    // 64*576*2    -> 31,907,840
#define PW_OFF   31907840u    // 32000*576*2 -> 68,771,840
#define LM_OFF   68771840u    // 32000*64*4  -> 76,963,840
#define W256_OFF 76963840u    // 1024*2      -> 76,965,888

typedef __attribute__((ext_vector_type(8))) __bf16 bf16x8;
typedef __attribute__((ext_vector_type(8))) unsigned short ushort8;
typedef __attribute__((ext_vector_type(4))) float  f32x4;

__device__ __forceinline__ void gload16(const void* g, void* l) {
  __builtin_amdgcn_global_load_lds((const __attribute__((address_space(1))) void*)g,
                                   (__attribute__((address_space(3))) void*)l, 16, 0, 0);
}
#define WAIT_VM(n)  asm volatile("s_waitcnt vmcnt(" #n ")" ::: "memory")
#define WAIT_LGKM0  asm volatile("s_waitcnt lgkmcnt(0)" ::: "memory")
#define BAR() __builtin_amdgcn_s_barrier()

__device__ __forceinline__ float bf2f(unsigned short u) {
  return __uint_as_float((unsigned)u << 16);
}

// ---------------- prepass: even/odd split + radix-2 weight tables ----------------
#define NG1 (NBATCH * (XHALF / 8))   // 962,048
#define NG2 ((1024 * 512) / 8)       // 65,536
#define NG3 ((NMEL * PSTR) / 8)      // 4,608
#define NG4 (1024 / 8)               // 128

__global__ void prep_kernel(const float* __restrict__ wav,
                            const float* __restrict__ wstft,
                            const float* __restrict__ mf,
                            unsigned char* __restrict__ ws) {
  __hip_bfloat16* xpE = (__hip_bfloat16*)(ws + XPE_OFF);
  __hip_bfloat16* xpO = (__hip_bfloat16*)(ws + XPO_OFF);
  __hip_bfloat16* weo = (__hip_bfloat16*)(ws + WEO_OFF);
  __hip_bfloat16* wmt = (__hip_bfloat16*)(ws + WMT_OFF);
  __hip_bfloat16* w256 = (__hip_bfloat16*)(ws + W256_OFF);
  int idx = blockIdx.x * blockDim.x + threadIdx.x;
  if (idx < NG1) {
    int b = idx / (XHALF / 8);
    int g = idx - b * (XHALF / 8);       // xpad positions [16g, 16g+16)
    const float* src = wav + (size_t)b * LWAV;
    __hip_bfloat16 e[8], o[8];
    if (g >= 32 && g <= 30030) {
      const float4* p = (const float4*)(src + 16 * g - 512);
#pragma unroll
      for (int u = 0; u < 4; ++u) {
        float4 v = p[u];
        e[2 * u]     = __float2bfloat16(v.x);
        o[2 * u]     = __float2bfloat16(v.y);
        e[2 * u + 1] = __float2bfloat16(v.z);
        o[2 * u + 1] = __float2bfloat16(v.w);
      }
    } else {
      for (int i = 0; i < 16; ++i) {
        int q = 16 * g + i;
        int s = q - 512;
        if (s < 0) s = -s;
        else if (s >= LWAV) s = 2 * (LWAV - 1) - s;
        __hip_bfloat16 v = __float2bfloat16(src[s]);
        if (i & 1) o[i >> 1] = v; else e[i >> 1] = v;
      }
    }
    *(uint4*)(xpE + (size_t)b * XHALF + 8 * g) = *(const uint4*)e;
    *(uint4*)(xpO + (size_t)b * XHALF + 8 * g) = *(const uint4*)o;
  } else if (idx < NG1 + NG2) {
    int v = idx - NG1;
    int row = v >> 6;                 // 0..1023 = comp*256 + j
    int mseg = (v & 63) * 8;
    int comp = row >> 8, j = row & 255;
    __hip_bfloat16 t[8];
    if (comp < 2) {
      const float4* srow = (const float4*)(wstft + (size_t)(comp == 0 ? j : 513 + j) * 1024 + 2 * mseg);
#pragma unroll
      for (int u = 0; u < 4; ++u) {
        float4 vv = srow[u];
        t[2 * u]     = __float2bfloat16(vv.x);
        t[2 * u + 1] = __float2bfloat16(vv.z);
      }
    } else {
      const float4* w0 = (const float4*)(wstft + 2 * mseg);
#pragma unroll
      for (int u = 0; u < 4; ++u) {
        float4 wwv = w0[u];
        float wo[2] = {wwv.y, wwv.w};
#pragma unroll
        for (int h = 0; h < 2; ++h) {
          int mm = mseg + 2 * u + h;
          int q = (j * mm) & 511;
          float ang = (float)q * 0.012271846f;    // 2*pi/512
          float val = (comp == 2) ? wo[h] * cosf(ang) : -wo[h] * sinf(ang);
          t[2 * u + h] = __float2bfloat16(val);
        }
      }
    }
    *(uint4*)(weo + (size_t)row * 512 + mseg) = *(const uint4*)t;
  } else if (idx < NG1 + NG2 + NG3) {
    int j = idx - NG1 - NG2;
    int n = j / (PSTR / 8);
    int k0 = (j - n * (PSTR / 8)) * 8;
    for (int k = k0; k < k0 + 8; ++k)
      wmt[n * PSTR + k] = __float2bfloat16(k < 513 ? mf[k * NMEL + n] : 0.0f);
  } else if (idx < NG1 + NG2 + NG3 + NG4) {
    int j = idx - NG1 - NG2 - NG3;
    int part = j >> 6;
    int m0 = (j & 63) * 8;
    __hip_bfloat16 t[8];
#pragma unroll
    for (int h = 0; h < 8; ++h) {
      int m = m0 + h;
      float v = part == 0 ? wstft[(size_t)256 * 1024 + 2 * m]
                          : wstft[(size_t)769 * 1024 + 2 * m + 1];
      t[h] = __float2bfloat16(v);
    }
    *(uint4*)(w256 + part * 512 + m0) = *(const uint4*)t;
  }
}

// ---------------- bin-256 kernel: writes pw[m][256] ----------------
__launch_bounds__(256, 2)
__global__ void p256_kernel(unsigned char* __restrict__ ws) {
  __hip_bfloat16* pw = (__hip_bfloat16*)(ws + PW_OFF);
  const int tid  = threadIdx.x;
  const int l16  = tid & 15;
  const int fidx = blockIdx.x * 16 + (tid >> 4);
  const int b = fidx / 1000, t = fidx - b * 1000;

  const unsigned short* xe = (const unsigned short*)(ws + XPE_OFF) +
      (size_t)b * XHALF + 240 * (size_t)t + l16 * 32;
  const unsigned short* xo = (const unsigned short*)(ws + XPO_OFF) +
      (size_t)b * XHALF + 240 * (size_t)t + l16 * 32;
  const unsigned short* we = (const unsigned short*)(ws + W256_OFF) + l16 * 32;
  const unsigned short* wo = (const unsigned short*)(ws + W256_OFF) + 512 + l16 * 32;

  ushort8 ev[4], ov[4], wev[4], wov[4];
#pragma unroll
  for (int q = 0; q < 4; ++q) {
    ev[q]  = *(const ushort8*)(xe + q * 8);
    ov[q]  = *(const ushort8*)(xo + q * 8);
    wev[q] = *(const ushort8*)(we + q * 8);
    wov[q] = *(const ushort8*)(wo + q * 8);
  }
  float dc = 0.f, ds = 0.f;
#pragma unroll
  for (int q = 0; q < 4; ++q)
#pragma unroll
    for (int u = 0; u < 8; ++u) {
      dc += bf2f(ev[q][u]) * bf2f(wev[q][u]);
      ds += bf2f(ov[q][u]) * bf2f(wov[q][u]);
    }
#pragma unroll
  for (int d = 1; d < 16; d <<= 1) {
    dc += __shfl_xor(dc, d);
    ds += __shfl_xor(ds, d);
  }
  if (l16 == 0)
    pw[((size_t)b * TOUT + t) * PSTR + 256] = __float2bfloat16(dc * dc + ds * ds);
}

// ---------------- STFT radix-2 GEMM: BM=128, 64 j x {Ec,Es,Oc,Os}, K=512, BK=32 ----
// 512 threads, 8 waves (2M x 4N): wave = 64 frames x (16 j x 4 comps = 64 B-rows).
// LDS holds A ONLY (dbuf 2x16KB = 32KB, 4x read multicast); B loads straight
// from L2 into registers (bX/bY 1-ktile prefetch) hidden under MFMA.
// Register budget (unified VGPR+AGPR): acc 64 + ae/ao 32 + bX/bY 32 + addr ~30
// ~= 160 < 256 at (512,1)  [R13 spill lesson: count AGPRs in the sum].
// vmcnt ledger (2 A-loads + 4 B-loads per thread per ktile, in-order):
// steady retire-A = vmcnt(6) (4 newer B + 2 newer A); prologue 6; tail 4.
#define STFT_NWG 1000
__launch_bounds__(512, 1)
__global__ void stft_kernel(unsigned char* __restrict__ ws) {
  __shared__ __align__(16) unsigned char lds[32768];  // A buf c @ c*16384
  __hip_bfloat16* pw = (__hip_bfloat16*)(ws + PW_OFF);

  const int tid  = threadIdx.x;
  const int lane = tid & 63;
  const int w    = tid >> 6;     // wave 0..7
  const int wm   = w >> 2;       // 0..1 m-half (64 frames)
  const int wn   = w & 3;        // 0..3 j-quad (16 j x 4 comps)

  // bijective XCD-chunked swizzle (nwg=1000: q=125, r=0), j-tile fastest
  const int orig = blockIdx.x;
  const int wg = (orig & 7) * 125 + (orig >> 3);
  const int j0 = (wg & 3) * 64;
  const int m0 = (wg >> 2) * 128;

  // ---- A staging: 2 loads/thread/ktile (pre-swizzled source, linear dest) ----
  // slot layout per 128B row: phys slot p holds content c = p ^ (row&7);
  // content 0..3 = E k-chunks, 4..7 = O k-chunks.
  const unsigned char* gsA[2];
  {
    int sl  = tid & 7;
    int rq  = tid >> 3;            // row within 64-row half (0..63)
    int slp = sl ^ (rq & 7);
#pragma unroll
    for (int i = 0; i < 2; ++i) {
      int row = i * 64 + rq;
      int m = m0 + row;
      int bb = m / 1000, tt = m - bb * 1000;
      size_t fb = ((size_t)bb * XHALF + 240 * (size_t)tt) * 2;
      gsA[i] = (slp < 4) ? (ws + XPE_OFF + fb + slp * 16)
                         : (ws + XPO_OFF + fb + (slp - 4) * 16);
    }
  }
#define STG_A(c, kt) do {                                                  \
    gload16(gsA[0] + (size_t)(kt) * 64, lds + (c) * 16384 + 0 * 8192 + w * 1024); \
    gload16(gsA[1] + (size_t)(kt) * 64, lds + (c) * 16384 + 1 * 8192 + w * 1024); \
  } while (0)

  // ---- B direct-from-global row pointers (4 per thread: comp = nf) ----
  const int l15 = lane & 15, lc = lane >> 4;   // lc = K chunk 0..3
  const unsigned char* gsBrow[4];
#pragma unroll
  for (int nf = 0; nf < 4; ++nf) {
    int jj = j0 + wn * 16 + l15;
    gsBrow[nf] = ws + WEO_OFF + (size_t)(nf * 256 + jj) * 1024 + lc * 16;
  }
#define LOAD_B(dst, kt) do {                                               \
    _Pragma("unroll")                                                      \
    for (int nf = 0; nf < 4; ++nf)                                         \
      dst[nf] = *(const bf16x8*)(gsBrow[nf] + (size_t)(kt) * 64);          \
  } while (0)

  // A fragment read base: row = wm*64 + mf*16 + l15 (row&7 == l15&7);
  // E phys slot = lc ^ (l15&7); O = same ^ 4 (i.e. byte ^ 64).
  const int aoffs = (wm * 64 + l15) * 128 + ((lc ^ (l15 & 7)) << 4);

  bf16x8 ae[4], ao[4], bX[4], bY[4];
  f32x4 acc[4][4];   // [mf][comp]
#pragma unroll
  for (int a = 0; a < 4; ++a)
#pragma unroll
    for (int b2 = 0; b2 < 4; ++b2) acc[a][b2] = (f32x4){0.f, 0.f, 0.f, 0.f};

#define RD_A(C) do {                                                       \
    _Pragma("unroll")                                                      \
    for (int mf = 0; mf < 4; ++mf) {                                       \
      ae[mf] = *(const bf16x8*)(lds + (C) + aoffs + mf * 2048);            \
      ao[mf] = *(const bf16x8*)(lds + (C) + (aoffs ^ 64) + mf * 2048);     \
    }                                                                      \
  } while (0)

#define MFMA_ALL(B) do {                                                   \
    __builtin_amdgcn_s_setprio(1);                                         \
    _Pragma("unroll")                                                      \
    for (int mf = 0; mf < 4; ++mf) {                                       \
      acc[mf][0] = __builtin_amdgcn_mfma_f32_16x16x32_bf16(                \
          ae[mf], B[0], acc[mf][0], 0, 0, 0);                              \
      acc[mf][1] = __builtin_amdgcn_mfma_f32_16x16x32_bf16(                \
          ae[mf], B[1], acc[mf][1], 0, 0, 0);                              \
      acc[mf][2] = __builtin_amdgcn_mfma_f32_16x16x32_bf16(                \
          ao[mf], B[2], acc[mf][2], 0, 0, 0);                              \
      acc[mf][3] = __builtin_amdgcn_mfma_f32_16x16x32_bf16(                \
          ao[mf], B[3], acc[mf][3], 0, 0, 0);                              \
    }                                                                      \
    __builtin_amdgcn_s_setprio(0);                                         \
  } while (0)

  // prologue: A k0->buf0, A k1->buf1 (4 loads), B k0 -> bX (4); retire A(k0)
  STG_A(0, 0);
  STG_A(1, 1);
  LOAD_B(bX, 0);
  WAIT_VM(6);
  BAR();

  for (int i = 0; i < 8; ++i) {
    const bool more = (i < 7);
    // ---- even ktile 2i (A buf0, B bX) ----
    RD_A(0);
    LOAD_B(bY, 2 * i + 1);
    MFMA_ALL(bX);
    WAIT_LGKM0;
    BAR();                                    // all waves done reading buf0
    if (more) {
      STG_A(0, (size_t)(2 * i + 2));          // overwrite buf0 with A(k+2)
      WAIT_VM(6);                             // retire A(2i+1)
    } else {
      WAIT_VM(4);                             // tail: retire A(15); B(15) newer
    }
    BAR();
    // ---- odd ktile 2i+1 (A buf1, B bY) ----
    RD_A(16384);
    if (more) LOAD_B(bX, 2 * i + 2);
    MFMA_ALL(bY);
    if (more) {
      WAIT_LGKM0;
      BAR();
      STG_A(1, (size_t)(2 * i + 3));
      WAIT_VM(6);                             // retire A(2i+2)
      BAR();
    }
  }

  // epilogue: twiddle-combine -> power bins j and 512-j (one j per lane)
  {
    int j = j0 + wn * 16 + l15;
    float th = (float)j * 0.0061359233f;   // pi/512
    float ct = cosf(th), st = sinf(th);
#pragma unroll
    for (int mf = 0; mf < 4; ++mf)
#pragma unroll
      for (int r = 0; r < 4; ++r) {
        int m = m0 + wm * 64 + mf * 16 + lc * 4 + r;
        float Ec = acc[mf][0][r], Es = acc[mf][1][r];
        float Oc = acc[mf][2][r], Os = acc[mf][3][r];
        float tOc = ct * Oc + st * Os;
        float tOs = ct * Os - st * Oc;
        float re1 = Ec + tOc, im1 = Es + tOs;
        float re2 = Ec - tOc, im2 = Es - tOs;
        pw[(size_t)m * PSTR + j]         = __float2bfloat16(re1 * re1 + im1 * im1);
        pw[(size_t)m * PSTR + (512 - j)] = __float2bfloat16(re2 * re2 + im2 * im2);
      }
  }
}

// ---------------- mel GEMM (K=576, BM=64) + log10 epilogue ----------------
__launch_bounds__(256, 4)
__global__ void mel_kernel(unsigned char* __restrict__ ws) {
  __shared__ __align__(16) unsigned char sA[64 * 128];
  __shared__ __align__(16) unsigned char sBt[64 * 128];
  const unsigned char* pwb  = ws + PW_OFF;
  const unsigned char* wmtb = ws + WMT_OFF;
  float* lm = (float*)(ws + LM_OFF);

  const int tid = threadIdx.x;
  const int lane = tid & 63;
  const int wid  = tid >> 6;
  const int m0 = blockIdx.x * 64;

  const int strow = tid >> 3;
  const int scol  = (tid & 7) << 4;

  const unsigned char* aptr[2];
  const unsigned char* bptr[2];
  unsigned char* aldst[2];
  unsigned char* bldst[2];
#pragma unroll
  for (int jj = 0; jj < 2; ++jj) {
    int rr = jj * 32 + strow;
    aptr[jj] = pwb + (size_t)(m0 + rr) * (PSTR * 2) + (scol ^ ((rr & 7) << 4));
    bptr[jj] = wmtb + (size_t)rr * (PSTR * 2) + (scol ^ ((rr & 7) << 4));
    aldst[jj] = &sA [jj * 4096 + wid * 1024];
    bldst[jj] = &sBt[jj * 4096 + wid * 1024];
  }

  f32x4 acc[4];
#pragma unroll
  for (int fr = 0; fr < 4; ++fr) acc[fr] = (f32x4){0.f, 0.f, 0.f, 0.f};

  for (int kk = 0; kk < PSTR; kk += 64) {
    __syncthreads();
#pragma unroll
    for (int jj = 0; jj < 2; ++jj) gload16(aptr[jj] + (size_t)kk * 2, aldst[jj]);
#pragma unroll
    for (int jj = 0; jj < 2; ++jj) gload16(bptr[jj] + (size_t)kk * 2, bldst[jj]);
    __syncthreads();
#pragma unroll
    for (int ks = 0; ks < 2; ++ks) {
      const int kby = ks * 64 + ((lane >> 4) << 4);
      bf16x8 af, bfr[4];
      {
        int rr = wid * 16 + (lane & 15);
        af = *(const bf16x8*)&sA[rr * 128 + (kby ^ ((rr & 7) << 4))];
      }
#pragma unroll
      for (int fr = 0; fr < 4; ++fr) {
        int rr = fr * 16 + (lane & 15);
        bfr[fr] = *(const bf16x8*)&sBt[rr * 128 + (kby ^ ((rr & 7) << 4))];
      }
#pragma unroll
      for (int fr = 0; fr < 4; ++fr)
        acc[fr] = __builtin_amdgcn_mfma_f32_16x16x32_bf16(af, bfr[fr], acc[fr], 0, 0, 0);
    }
  }

  const int col = lane & 15;
  const int rg  = lane >> 4;
#pragma unroll
  for (int fr = 0; fr < 4; ++fr) {
    int n = fr * 16 + col;
#pragma unroll
    for (int rr = 0; rr < 4; ++rr) {
      int mrow = wid * 16 + rg * 4 + rr;
      float v = acc[fr][rr];
      lm[(size_t)(m0 + mrow) * NMEL + n] = 10.0f * log10f(fmaxf(v, 1e-10f));
    }
  }
}

// ---------------- bilinear (time-axis only) interp ----------------
__global__ void interp_kernel(const unsigned char* __restrict__ ws, float* __restrict__ out) {
  const float* lm = (const float*)(ws + LM_OFF);
  int idx = blockIdx.x * blockDim.x + threadIdx.x;
  if (idx >= NBATCH * SPECW * 16) return;
  int m4 = idx & 15;
  int h  = (idx >> 4) & (SPECW - 1);
  int b  = idx >> 14;
  const float scale = (float)(999.0 / 1023.0);
  float pos = (float)h * scale;
  int i0 = (int)floorf(pos);
  if (i0 > TOUT - 1) i0 = TOUT - 1;
  float wgt = pos - (float)i0;
  int i1 = i0 + 1;
  if (i1 > TOUT - 1) i1 = TOUT - 1;
  const float4* r0 = (const float4*)(lm + ((size_t)b * TOUT + i0) * NMEL);
  const float4* r1 = (const float4*)(lm + ((size_t)b * TOUT + i1) * NMEL);
  float4 a = r0[m4], c = r1[m4];
  float4 o;
  o.x = a.x * (1.0f - wgt) + c.x * wgt;
  o.y = a.y * (1.0f - wgt) + c.y * wgt;
  o.z = a.z * (1.0f - wgt) + c.z * wgt;
  o.w = a.w * (1.0f - wgt) + c.w * wgt;
  ((float4*)out)[idx] = o;
}

extern "C" void kernel_launch(void* const* d_in, const int* in_sizes, int n_in,
                              void* d_out, int out_size, void* d_ws, size_t ws_size,
                              hipStream_t stream) {
  (void)in_sizes; (void)n_in; (void)out_size; (void)ws_size;
  const float* wav   = (const float*)d_in[0];
  const float* wstft = (const float*)d_in[1];
  const float* mf    = (const float*)d_in[2];
  unsigned char* ws  = (unsigned char*)d_ws;
  float* out = (float*)d_out;

  const int tot = NG1 + NG2 + NG3 + NG4;
  prep_kernel<<<(tot + 255) / 256, 256, 0, stream>>>(wav, wstft, mf, ws);
  stft_kernel<<<STFT_NWG, 512, 0, stream>>>(ws);
  p256_kernel<<<2000, 256, 0, stream>>>(ws);
  mel_kernel<<<500, 256, 0, stream>>>(ws);
  interp_kernel<<<(NBATCH * SPECW * 16) / 256, 256, 0, stream>>>(ws, out);
}

// Round 15
// 90.622 us; speedup vs baseline: 1.5689x; 1.4941x over previous
//
#include <hip/hip_runtime.h>
#include <hip/hip_bf16.h>
#include <math.h>

#define LWAV   480000
#define XHALF  240512      // xpad length / 2
#define NBATCH 32
#define TOUT   1000
#define NMEL   64
#define PSTR   576
#define SPECW  1024

// workspace layout (bytes), 16B-aligned
#define XPE_OFF  0u           // 32*240512*2 = 15,392,768
#define XPO_OFF  15392768u    // 32*240512*2 -> 30,785,536
#define WEO_OFF  30785536u    // 1024*512*2  -> 31,834,112
#define WMT_OFF  31834112u    // 64*576*2    -> 31,907,840
#define PW_OFF   31907840u    // 32000*576*2 -> 68,771,840
#define LM_OFF   68771840u    // 32000*64*4  -> 76,963,840
#define W256_OFF 76963840u    // 1024*2      -> 76,965,888

typedef __attribute__((ext_vector_type(8))) __bf16 bf16x8;
typedef __attribute__((ext_vector_type(8))) unsigned short ushort8;
typedef __attribute__((ext_vector_type(4))) float  f32x4;

__device__ __forceinline__ void gload16(const void* g, void* l) {
  __builtin_amdgcn_global_load_lds((const __attribute__((address_space(1))) void*)g,
                                   (__attribute__((address_space(3))) void*)l, 16, 0, 0);
}
#define WAIT_VM(n)  asm volatile("s_waitcnt vmcnt(" #n ")" ::: "memory")
#define BAR() __builtin_amdgcn_s_barrier()

__device__ __forceinline__ float bf2f(unsigned short u) {
  return __uint_as_float((unsigned)u << 16);
}

// ---------------- prepass: even/odd split + radix-2 weight tables ----------------
#define NG1 (NBATCH * (XHALF / 8))   // 962,048
#define NG2 ((1024 * 512) / 8)       // 65,536
#define NG3 ((NMEL * PSTR) / 8)      // 4,608
#define NG4 (1024 / 8)               // 128

__global__ void prep_kernel(const float* __restrict__ wav,
                            const float* __restrict__ wstft,
                            const float* __restrict__ mf,
                            unsigned char* __restrict__ ws) {
  __hip_bfloat16* xpE = (__hip_bfloat16*)(ws + XPE_OFF);
  __hip_bfloat16* xpO = (__hip_bfloat16*)(ws + XPO_OFF);
  __hip_bfloat16* weo = (__hip_bfloat16*)(ws + WEO_OFF);
  __hip_bfloat16* wmt = (__hip_bfloat16*)(ws + WMT_OFF);
  __hip_bfloat16* w256 = (__hip_bfloat16*)(ws + W256_OFF);
  int idx = blockIdx.x * blockDim.x + threadIdx.x;
  if (idx < NG1) {
    int b = idx / (XHALF / 8);
    int g = idx - b * (XHALF / 8);       // xpad positions [16g, 16g+16)
    const float* src = wav + (size_t)b * LWAV;
    __hip_bfloat16 e[8], o[8];
    if (g >= 32 && g <= 30030) {
      const float4* p = (const float4*)(src + 16 * g - 512);
#pragma unroll
      for (int u = 0; u < 4; ++u) {
        float4 v = p[u];
        e[2 * u]     = __float2bfloat16(v.x);
        o[2 * u]     = __float2bfloat16(v.y);
        e[2 * u + 1] = __float2bfloat16(v.z);
        o[2 * u + 1] = __float2bfloat16(v.w);
      }
    } else {
      for (int i = 0; i < 16; ++i) {
        int q = 16 * g + i;
        int s = q - 512;
        if (s < 0) s = -s;
        else if (s >= LWAV) s = 2 * (LWAV - 1) - s;
        __hip_bfloat16 v = __float2bfloat16(src[s]);
        if (i & 1) o[i >> 1] = v; else e[i >> 1] = v;
      }
    }
    *(uint4*)(xpE + (size_t)b * XHALF + 8 * g) = *(const uint4*)e;
    *(uint4*)(xpO + (size_t)b * XHALF + 8 * g) = *(const uint4*)o;
  } else if (idx < NG1 + NG2) {
    int v = idx - NG1;
    int row = v >> 6;                 // 0..1023 = comp*256 + j
    int mseg = (v & 63) * 8;
    int comp = row >> 8, j = row & 255;
    __hip_bfloat16 t[8];
    if (comp < 2) {
      const float4* srow = (const float4*)(wstft + (size_t)(comp == 0 ? j : 513 + j) * 1024 + 2 * mseg);
#pragma unroll
      for (int u = 0; u < 4; ++u) {
        float4 vv = srow[u];
        t[2 * u]     = __float2bfloat16(vv.x);
        t[2 * u + 1] = __float2bfloat16(vv.z);
      }
    } else {
      const float4* w0 = (const float4*)(wstft + 2 * mseg);
#pragma unroll
      for (int u = 0; u < 4; ++u) {
        float4 wwv = w0[u];
        float wo[2] = {wwv.y, wwv.w};
#pragma unroll
        for (int h = 0; h < 2; ++h) {
          int mm = mseg + 2 * u + h;
          int q = (j * mm) & 511;
          float ang = (float)q * 0.012271846f;    // 2*pi/512
          float val = (comp == 2) ? wo[h] * cosf(ang) : -wo[h] * sinf(ang);
          t[2 * u + h] = __float2bfloat16(val);
        }
      }
    }
    *(uint4*)(weo + (size_t)row * 512 + mseg) = *(const uint4*)t;
  } else if (idx < NG1 + NG2 + NG3) {
    int j = idx - NG1 - NG2;
    int n = j / (PSTR / 8);
    int k0 = (j - n * (PSTR / 8)) * 8;
    for (int k = k0; k < k0 + 8; ++k)
      wmt[n * PSTR + k] = __float2bfloat16(k < 513 ? mf[k * NMEL + n] : 0.0f);
  } else if (idx < NG1 + NG2 + NG3 + NG4) {
    int j = idx - NG1 - NG2 - NG3;
    int part = j >> 6;
    int m0 = (j & 63) * 8;
    __hip_bfloat16 t[8];
#pragma unroll
    for (int h = 0; h < 8; ++h) {
      int m = m0 + h;
      float v = part == 0 ? wstft[(size_t)256 * 1024 + 2 * m]
                          : wstft[(size_t)769 * 1024 + 2 * m + 1];
      t[h] = __float2bfloat16(v);
    }
    *(uint4*)(w256 + part * 512 + m0) = *(const uint4*)t;
  }
}

// ---------------- STFT radix-2 GEMM (R10-proven 52.5us) + folded p256 ----
// Blocks [0,500): BM=256, 64 j x {Ec,Es,Oc,Os}, K=512, BK=32. Triple-buffered
// 48KB sets, 1 barrier + vmcnt(6) per ktile, 2-deep prefetch, twiddle epilogue.
// Blocks [500,1500): bin-256 dot products (32 frames/block, 16 lanes/frame).
#define STFT_NWG 500
__launch_bounds__(512, 1)
__global__ void stft_kernel(unsigned char* __restrict__ ws) {
  __shared__ __align__(16) unsigned char lds[147456];   // 3 x (A 32768 + B 16384)
  __hip_bfloat16* pw = (__hip_bfloat16*)(ws + PW_OFF);

  // ---------- folded p256 path ----------
  if (blockIdx.x >= STFT_NWG) {
    const int tid = threadIdx.x;
    const int l16 = tid & 15;
    const int fidx = (blockIdx.x - STFT_NWG) * 32 + (tid >> 4);
    if (fidx < NBATCH * TOUT) {
      const int b = fidx / 1000, t = fidx - b * 1000;
      const unsigned short* xe = (const unsigned short*)(ws + XPE_OFF) +
          (size_t)b * XHALF + 240 * (size_t)t + l16 * 32;
      const unsigned short* xo = (const unsigned short*)(ws + XPO_OFF) +
          (size_t)b * XHALF + 240 * (size_t)t + l16 * 32;
      const unsigned short* we = (const unsigned short*)(ws + W256_OFF) + l16 * 32;
      const unsigned short* wo = (const unsigned short*)(ws + W256_OFF) + 512 + l16 * 32;
      ushort8 ev[4], ov[4], wev[4], wov[4];
#pragma unroll
      for (int q = 0; q < 4; ++q) {
        ev[q]  = *(const ushort8*)(xe + q * 8);
        ov[q]  = *(const ushort8*)(xo + q * 8);
        wev[q] = *(const ushort8*)(we + q * 8);
        wov[q] = *(const ushort8*)(wo + q * 8);
      }
      float dc = 0.f, dsn = 0.f;
#pragma unroll
      for (int q = 0; q < 4; ++q)
#pragma unroll
        for (int u = 0; u < 8; ++u) {
          dc  += bf2f(ev[q][u]) * bf2f(wev[q][u]);
          dsn += bf2f(ov[q][u]) * bf2f(wov[q][u]);
        }
#pragma unroll
      for (int d = 1; d < 16; d <<= 1) {
        dc  += __shfl_xor(dc, d);
        dsn += __shfl_xor(dsn, d);
      }
      if (l16 == 0)
        pw[((size_t)b * TOUT + t) * PSTR + 256] = __float2bfloat16(dc * dc + dsn * dsn);
    }
    return;
  }

  // ---------- stft GEMM path (verbatim R10) ----------
  const int tid  = threadIdx.x;
  const int lane = tid & 63;
  const int w    = tid >> 6;
  const int wm   = w >> 2;
  const int wc   = w & 3;

  // bijective XCD-chunked swizzle (nwg=500: q=62, r=4), j-tile fastest
  const int orig = blockIdx.x;
  const int q8 = STFT_NWG / 8, r8 = STFT_NWG % 8;
  const int xcd = orig & 7;
  const int wg = (xcd < r8 ? xcd * (q8 + 1) : r8 * (q8 + 1) + (xcd - r8) * q8) + (orig >> 3);
  const int j0 = (wg & 3) * 64;
  const int m0 = (wg >> 2) * 256;

  // staging sources (per-thread, pre-swizzled; +64B per ktile)
  const unsigned char* gsA[4];
  const unsigned char* gsB[2];
#pragma unroll
  for (int i = 0; i < 4; ++i) {
    int r = (w * 4 + i) * 8 + (lane >> 3);
    int q = lane & 7;
    int l1 = q ^ (r & 7);
    int m = m0 + r;
    int bb = m / 1000, tt = m - bb * 1000;
    size_t fbase = ((size_t)bb * XHALF + 240 * (size_t)tt) * 2;
    gsA[i] = (l1 < 4) ? (ws + XPE_OFF + fbase + l1 * 16)
                      : (ws + XPO_OFF + fbase + (l1 - 4) * 16);
  }
#pragma unroll
  for (int i = 0; i < 2; ++i) {
    int r = (w * 2 + i) * 16 + (lane >> 2);
    int q = lane & 3;
    int l2 = q ^ ((r >> 1) & 3);
    int comp = (r >> 4) & 3;
    int jv = j0 + (r >> 6) * 16 + (r & 15);
    gsB[i] = ws + WEO_OFF + ((size_t)(comp * 256 + jv) * 512) * 2 + l2 * 16;
  }

#define STG(c, kt) do {                                                          \
    gload16(gsA[0] + (size_t)(kt) * 64, lds + (c) * 49152 + (w * 4 + 0) * 1024); \
    gload16(gsA[1] + (size_t)(kt) * 64, lds + (c) * 49152 + (w * 4 + 1) * 1024); \
    gload16(gsA[2] + (size_t)(kt) * 64, lds + (c) * 49152 + (w * 4 + 2) * 1024); \
    gload16(gsA[3] + (size_t)(kt) * 64, lds + (c) * 49152 + (w * 4 + 3) * 1024); \
    gload16(gsB[0] + (size_t)(kt) * 64, lds + (c) * 49152 + 32768 + (w * 2 + 0) * 1024); \
    gload16(gsB[1] + (size_t)(kt) * 64, lds + (c) * 49152 + 32768 + (w * 2 + 1) * 1024); \
  } while (0)

  // fragment read bases (lane-invariant XOR; row&7 == l15&7, (row>>1)&3 == (l15>>1)&3)
  const int l15 = lane & 15, lc = lane >> 4;
  const int swA = (lc ^ (l15 & 7)) << 4;
  const unsigned char* aeB = lds + (wm * 128 + l15) * 128 + swA;
  const unsigned char* aoB = lds + (wm * 128 + l15) * 128 + (swA ^ 64);
  const int swB = (lc ^ ((l15 >> 1) & 3)) << 4;
  const unsigned char* bB = lds + 32768 + (wc * 64 + l15) * 64 + swB;

  bf16x8 ae[8], ao[8], bfr[4];
  f32x4 acc[8][4];
#pragma unroll
  for (int a = 0; a < 8; ++a)
#pragma unroll
    for (int b2 = 0; b2 < 4; ++b2) acc[a][b2] = (f32x4){0.f, 0.f, 0.f, 0.f};

  // prologue: stage k0->buf0, k1->buf1 (12 loads); retire k0
  STG(0, 0);
  STG(1, 1);
  WAIT_VM(6);
  BAR();

#pragma unroll
  for (int kt = 0; kt < 16; ++kt) {
    const int cur = kt % 3;
    if (kt + 2 < 16) STG((kt + 2) % 3, kt + 2);
#pragma unroll
    for (int mf = 0; mf < 8; ++mf)
      ae[mf] = *(const bf16x8*)(aeB + cur * 49152 + mf * 2048);
#pragma unroll
    for (int nf = 0; nf < 4; ++nf)
      bfr[nf] = *(const bf16x8*)(bB + cur * 49152 + nf * 1024);
    __builtin_amdgcn_s_setprio(1);
#pragma unroll
    for (int mf = 0; mf < 8; ++mf) {
      acc[mf][0] = __builtin_amdgcn_mfma_f32_16x16x32_bf16(ae[mf], bfr[0], acc[mf][0], 0, 0, 0);
      acc[mf][1] = __builtin_amdgcn_mfma_f32_16x16x32_bf16(ae[mf], bfr[1], acc[mf][1], 0, 0, 0);
    }
    __builtin_amdgcn_s_setprio(0);
#pragma unroll
    for (int mf = 0; mf < 8; ++mf)
      ao[mf] = *(const bf16x8*)(aoB + cur * 49152 + mf * 2048);
    __builtin_amdgcn_s_setprio(1);
#pragma unroll
    for (int mf = 0; mf < 8; ++mf) {
      acc[mf][2] = __builtin_amdgcn_mfma_f32_16x16x32_bf16(ao[mf], bfr[2], acc[mf][2], 0, 0, 0);
      acc[mf][3] = __builtin_amdgcn_mfma_f32_16x16x32_bf16(ao[mf], bfr[3], acc[mf][3], 0, 0, 0);
    }
    __builtin_amdgcn_s_setprio(0);
    if (kt < 14) { WAIT_VM(6); BAR(); }
    else if (kt == 14) { WAIT_VM(0); BAR(); }
  }

  // epilogue: twiddle-combine -> power bins j and 512-j
  const int j = j0 + wc * 16 + l15;
  const float th = (float)j * 0.0061359233f;   // pi/512
  const float ct = cosf(th), st = sinf(th);
#pragma unroll
  for (int mf = 0; mf < 8; ++mf)
#pragma unroll
    for (int r = 0; r < 4; ++r) {
      int m = m0 + wm * 128 + mf * 16 + lc * 4 + r;
      float Ec = acc[mf][0][r], Es = acc[mf][1][r];
      float Oc = acc[mf][2][r], Os = acc[mf][3][r];
      float tOc = ct * Oc + st * Os;
      float tOs = ct * Os - st * Oc;
      float re1 = Ec + tOc, im1 = Es + tOs;
      float re2 = Ec - tOc, im2 = Es - tOs;
      pw[(size_t)m * PSTR + j]         = __float2bfloat16(re1 * re1 + im1 * im1);
      pw[(size_t)m * PSTR + (512 - j)] = __float2bfloat16(re2 * re2 + im2 * im2);
    }
}

// ---------------- mel GEMM (K=576, BM=64) + log10 epilogue ----------------
__launch_bounds__(256, 4)
__global__ void mel_kernel(unsigned char* __restrict__ ws) {
  __shared__ __align__(16) unsigned char sA[64 * 128];
  __shared__ __align__(16) unsigned char sBt[64 * 128];
  const unsigned char* pwb  = ws + PW_OFF;
  const unsigned char* wmtb = ws + WMT_OFF;
  float* lm = (float*)(ws + LM_OFF);

  const int tid = threadIdx.x;
  const int lane = tid & 63;
  const int wid  = tid >> 6;
  const int m0 = blockIdx.x * 64;

  const int strow = tid >> 3;
  const int scol  = (tid & 7) << 4;

  const unsigned char* aptr[2];
  const unsigned char* bptr[2];
  unsigned char* aldst[2];
  unsigned char* bldst[2];
#pragma unroll
  for (int jj = 0; jj < 2; ++jj) {
    int rr = jj * 32 + strow;
    aptr[jj] = pwb + (size_t)(m0 + rr) * (PSTR * 2) + (scol ^ ((rr & 7) << 4));
    bptr[jj] = wmtb + (size_t)rr * (PSTR * 2) + (scol ^ ((rr & 7) << 4));
    aldst[jj] = &sA [jj * 4096 + wid * 1024];
    bldst[jj] = &sBt[jj * 4096 + wid * 1024];
  }

  f32x4 acc[4];
#pragma unroll
  for (int fr = 0; fr < 4; ++fr) acc[fr] = (f32x4){0.f, 0.f, 0.f, 0.f};

  for (int kk = 0; kk < PSTR; kk += 64) {
    __syncthreads();
#pragma unroll
    for (int jj = 0; jj < 2; ++jj) gload16(aptr[jj] + (size_t)kk * 2, aldst[jj]);
#pragma unroll
    for (int jj = 0; jj < 2; ++jj) gload16(bptr[jj] + (size_t)kk * 2, bldst[jj]);
    __syncthreads();
#pragma unroll
    for (int ks = 0; ks < 2; ++ks) {
      const int kby = ks * 64 + ((lane >> 4) << 4);
      bf16x8 af, bfr[4];
      {
        int rr = wid * 16 + (lane & 15);
        af = *(const bf16x8*)&sA[rr * 128 + (kby ^ ((rr & 7) << 4))];
      }
#pragma unroll
      for (int fr = 0; fr < 4; ++fr) {
        int rr = fr * 16 + (lane & 15);
        bfr[fr] = *(const bf16x8*)&sBt[rr * 128 + (kby ^ ((rr & 7) << 4))];
      }
#pragma unroll
      for (int fr = 0; fr < 4; ++fr)
        acc[fr] = __builtin_amdgcn_mfma_f32_16x16x32_bf16(af, bfr[fr], acc[fr], 0, 0, 0);
    }
  }

  const int col = lane & 15;
  const int rg  = lane >> 4;
#pragma unroll
  for (int fr = 0; fr < 4; ++fr) {
    int n = fr * 16 + col;
#pragma unroll
    for (int rr = 0; rr < 4; ++rr) {
      int mrow = wid * 16 + rg * 4 + rr;
      float v = acc[fr][rr];
      lm[(size_t)(m0 + mrow) * NMEL + n] = 10.0f * log10f(fmaxf(v, 1e-10f));
    }
  }
}

// ---------------- bilinear (time-axis only) interp ----------------
__global__ void interp_kernel(const unsigned char* __restrict__ ws, float* __restrict__ out) {
  const float* lm = (const float*)(ws + LM_OFF);
  int idx = blockIdx.x * blockDim.x + threadIdx.x;
  if (idx >= NBATCH * SPECW * 16) return;
  int m4 = idx & 15;
  int h  = (idx >> 4) & (SPECW - 1);
  int b  = idx >> 14;
  const float scale = (float)(999.0 / 1023.0);
  float pos = (float)h * scale;
  int i0 = (int)floorf(pos);
  if (i0 > TOUT - 1) i0 = TOUT - 1;
  float wgt = pos - (float)i0;
  int i1 = i0 + 1;
  if (i1 > TOUT - 1) i1 = TOUT - 1;
  const float4* r0 = (const float4*)(lm + ((size_t)b * TOUT + i0) * NMEL);
  const float4* r1 = (const float4*)(lm + ((size_t)b * TOUT + i1) * NMEL);
  float4 a = r0[m4], c = r1[m4];
  float4 o;
  o.x = a.x * (1.0f - wgt) + c.x * wgt;
  o.y = a.y * (1.0f - wgt) + c.y * wgt;
  o.z = a.z * (1.0f - wgt) + c.z * wgt;
  o.w = a.w * (1.0f - wgt) + c.w * wgt;
  ((float4*)out)[idx] = o;
}

extern "C" void kernel_launch(void* const* d_in, const int* in_sizes, int n_in,
                              void* d_out, int out_size, void* d_ws, size_t ws_size,
                              hipStream_t stream) {
  (void)in_sizes; (void)n_in; (void)out_size; (void)ws_size;
  const float* wav   = (const float*)d_in[0];
  const float* wstft = (const float*)d_in[1];
  const float* mf    = (const float*)d_in[2];
  unsigned char* ws  = (unsigned char*)d_ws;
  float* out = (float*)d_out;

  const int tot = NG1 + NG2 + NG3 + NG4;
  prep_kernel<<<(tot + 255) / 256, 256, 0, stream>>>(wav, wstft, mf, ws);
  // blocks [0,500): radix-2 GEMM; blocks [500,1500): bin-256 dots (32 frames each)
  stft_kernel<<<STFT_NWG + 1000, 512, 0, stream>>>(ws);
  mel_kernel<<<500, 256, 0, stream>>>(ws);
  interp_kernel<<<(NBATCH * SPECW * 16) / 256, 256, 0, stream>>>(ws, out);
}